// Round 10
// baseline (3550.014 us; speedup 1.0000x reference)
//
#include <hip/hip_runtime.h>
#include <cstdint>
#include <cstddef>

typedef _Float16 half8  __attribute__((ext_vector_type(8)));
typedef _Float16 half2v __attribute__((ext_vector_type(2)));
typedef float    floatx4 __attribute__((ext_vector_type(4)));
typedef unsigned uint4v  __attribute__((ext_vector_type(4)));

#define B_  64
#define T_  512
#define D_  512
#define H_  512
#define NG  2048   // 4*H

#if defined(__has_builtin)
#if __has_builtin(__builtin_amdgcn_fdot2)
#define HAVE_FDOT2 1
#endif
#endif

static __device__ __forceinline__ float fdot2_acc(half2v a, half2v b, float c) {
#ifdef HAVE_FDOT2
  return __builtin_amdgcn_fdot2(a, b, c, false);
#else
  return fmaf((float)a[0], (float)b[0], fmaf((float)a[1], (float)b[1], c));
#endif
}
static __device__ __forceinline__ half2v h2(half8 v, int i) {
  half2v r; r[0] = v[2*i]; r[1] = v[2*i+1]; return r;
}
static __device__ __forceinline__ float fast_sigmoid(float x) {
  return 1.0f / (1.0f + __expf(-x));
}
static __device__ __forceinline__ float fast_tanh(float x) {
  x = fminf(15.0f, fmaxf(-15.0f, x));
  float e = __expf(2.0f * x);
  return (e - 1.0f) / (e + 1.0f);
}

// LDS-only barrier: drains lgkmcnt but NOT vmcnt (global ops stay in flight).
#define LDS_BARRIER() do {                                   \
    asm volatile("s_waitcnt lgkmcnt(0)" ::: "memory");       \
    __builtin_amdgcn_s_barrier();                            \
  } while (0)

// ---------------------------------------------------------------------------
// Kernel 1: input projections (unchanged — measured ~0.17 ms)
// ---------------------------------------------------------------------------
__global__ __launch_bounds__(256) void proj_kernel(
    const float* __restrict__ x,
    const float* __restrict__ Wc, const float* __restrict__ Wi,
    const float* __restrict__ Wf, const float* __restrict__ Wo,
    const float* __restrict__ bc, const float* __restrict__ bi,
    const float* __restrict__ bf2, const float* __restrict__ bo,
    _Float16* __restrict__ XG)
{
  const int tiles_n = NG / 64;
  int tM = blockIdx.x / tiles_n;
  int tN = blockIdx.x % tiles_n;
  int r0 = tM * 64;
  int t0 = r0 >> 6;
  int n0 = tN * 64;
  int g  = n0 >> 9;
  const float* W    = (g==0) ? Wc : (g==1) ? Wi : (g==2) ? Wf : Wo;
  const float* bias = (g==0) ? bc : (g==1) ? bi : (g==2) ? bf2 : bo;
  int j0 = n0 & (H_-1);

  __shared__ _Float16 Al[64*40];
  __shared__ _Float16 Bl[64*40];

  int tid  = threadIdx.x;
  int wave = tid >> 6;
  int lane = tid & 63;

  floatx4 acc[4] = {};

  int arow = tid >> 2;
  int ak0  = (tid & 3) * 8;
  const float* xsrc = x + ((size_t)arow * T_ + t0) * D_;

  int bcol = tid & 63;
  int bk0  = (tid >> 6) * 8;

  for (int k0 = 0; k0 < D_; k0 += 32) {
    half8 av;
    #pragma unroll
    for (int i = 0; i < 8; ++i) av[i] = (_Float16)xsrc[k0 + ak0 + i];
    *(half8*)&Al[arow*40 + ak0] = av;

    half8 bv;
    #pragma unroll
    for (int i = 0; i < 8; ++i)
      bv[i] = (_Float16)W[(size_t)(k0 + bk0 + i) * H_ + j0 + bcol];
    *(half8*)&Bl[bcol*40 + bk0] = bv;

    __syncthreads();

    half8 afrag = *(half8*)&Al[(wave*16 + (lane & 15))*40 + (lane >> 4)*8];
    #pragma unroll
    for (int ct = 0; ct < 4; ++ct) {
      half8 bfrag = *(half8*)&Bl[(ct*16 + (lane & 15))*40 + (lane >> 4)*8];
      acc[ct] = __builtin_amdgcn_mfma_f32_16x16x32_f16(afrag, bfrag, acc[ct], 0, 0, 0);
    }
    __syncthreads();
  }

  #pragma unroll
  for (int ct = 0; ct < 4; ++ct) {
    int col = n0 + ct*16 + (lane & 15);
    float bvs = bias[col & (H_-1)];
    #pragma unroll
    for (int i = 0; i < 4; ++i) {
      int row = r0 + wave*16 + (lane >> 4)*4 + i;
      XG[(size_t)row * NG + col] = (_Float16)(acc[ct][i] + bvs);
    }
  }
}

// ---------------------------------------------------------------------------
// Kernel 2: persistent scan, v10 — dual-path tagged handoff, SAFE fast path.
//   Producer: volatile store -> local-XCD L2 (write-through L1) AND agent
//   atomic store -> MALL (truth). Consumer: fast sweeps read fast_buf via
//   ONE monolithic asm block (4x global_load_dwordx4 sc0 + s_waitcnt inside,
//   data as block outputs -> no reorder window); every 4th sweep reads
//   true_buf with compiler-emitted agent atomics (guaranteed progress).
//   Tag-in-word self-validates both paths; placement only affects speed.
// ---------------------------------------------------------------------------
#define SH 520   // f16 row stride

__global__ __launch_bounds__(256) void scan_kernel(
    const _Float16* __restrict__ XG,
    const float* __restrict__ Uc, const float* __restrict__ Ui,
    const float* __restrict__ Uf, const float* __restrict__ Uo,
    float* __restrict__ out,
    unsigned* __restrict__ fast_buf, unsigned* __restrict__ true_buf)
{
  extern __shared__ _Float16 lds[];
  _Float16* U_lds = lds;                       // 64 rows x SH (row = g*16+jj)
  _Float16* h_lds = lds + 64*SH;               // 8 rows x SH
  float*  act_buf = (float*)(lds + 72*SH);     // 128*2 f32 activated i,o

  int tid = threadIdx.x;
  int grp = blockIdx.x & 7;
  int member = blockIdx.x >> 3;
  int j0 = member * 16;

  { // one-time: stage U columns transposed into LDS, f32 -> f16
    int jj = tid & 15;
    int kk = tid >> 4;
    #pragma unroll
    for (int g = 0; g < 4; ++g) {
      const float* U = (g==0) ? Uc : (g==1) ? Ui : (g==2) ? Uf : Uo;
      _Float16* dst = &U_lds[(g*16 + jj)*SH];
      for (int k = kk; k < H_; k += 16)
        dst[k] = (_Float16)U[(size_t)k * H_ + j0 + jj];
    }
  }
  __syncthreads();

  // compute mapping: local = b*16+jj within this member's 128-word block
  int gh    = tid >> 7;
  int local = tid & 127;
  int b     = local >> 4;
  int jj    = local & 15;
  int bglob = grp*8 + b;
  int j = j0 + jj;

  const half8* Ur0 = (const half8*)&U_lds[((gh    )*16 + jj)*SH];
  const half8* Ur1 = (const half8*)&U_lds[((gh + 2)*16 + jj)*SH];
  const half8* Hr  = (const half8*)&h_lds[b*SH];

  // consumer geometry: thread reads words [tid*16, tid*16+16) of the group
  // block (contiguous 64B) -> member = tid>>3, batch row = tid&7
  int cb  = tid & 7;
  int cj0 = (tid >> 3) * 16;

  float c_reg = 0.0f;

  // preload XG for t=0
  float xg0, xg1;
  {
    size_t xb = (size_t)bglob * NG;
    xg0 = (float)XG[xb + (size_t)gh*H_ + j];
    xg1 = (float)XG[xb + (size_t)(gh + 2)*H_ + j];
  }

  for (int t = 0; t < T_; ++t) {
    // ---- stage h^t: dual-path tagged poll ----
    {
      unsigned base = ((unsigned)(t & 1))*32768u + (unsigned)grp*4096u
                    + (unsigned)tid*16u;
      const unsigned* fsrc = fast_buf + base;
      const unsigned long long* tq = (const unsigned long long*)(true_buf + base);
      unsigned want = (unsigned)t & 0xFFFFu;

      unsigned w[16];
      int sweep = 0;
      for (;;) {
        if ((sweep & 3) == 3) {
          // truth sweep: compiler-emitted agent atomics (MALL) — progress
          unsigned long long q8[8];
          #pragma unroll
          for (int q = 0; q < 8; ++q)
            q8[q] = __hip_atomic_load(tq + q, __ATOMIC_RELAXED,
                                      __HIP_MEMORY_SCOPE_AGENT);
          #pragma unroll
          for (int q = 0; q < 8; ++q) {
            w[2*q]   = (unsigned)q8[q];
            w[2*q+1] = (unsigned)(q8[q] >> 32);
          }
        } else {
          // fast sweep: monolithic asm block — loads + waitcnt inseparable,
          // data are block OUTPUTS so no use can precede the waitcnt.
          uint4v va, vb, vc, vd;
          asm volatile(
            "global_load_dwordx4 %0, %4, off sc0\n\t"
            "global_load_dwordx4 %1, %4, off offset:16 sc0\n\t"
            "global_load_dwordx4 %2, %4, off offset:32 sc0\n\t"
            "global_load_dwordx4 %3, %4, off offset:48 sc0\n\t"
            "s_waitcnt vmcnt(0)"
            : "=&v"(va), "=&v"(vb), "=&v"(vc), "=&v"(vd)
            : "v"(fsrc)
            : "memory");
          __builtin_amdgcn_sched_barrier(0);
          #pragma unroll
          for (int i = 0; i < 4; ++i) {
            w[i]    = va[i];
            w[4+i]  = vb[i];
            w[8+i]  = vc[i];
            w[12+i] = vd[i];
          }
        }
        unsigned diff = 0;
        #pragma unroll
        for (int i = 0; i < 16; ++i) diff |= (w[i] ^ want) & 0xFFFFu;
        if (!diff) break;
        __builtin_amdgcn_s_sleep(1);
        ++sweep;
      }
      half8 hv0, hv1;
      #pragma unroll
      for (int i = 0; i < 8; ++i) {
        hv0[i] = __builtin_bit_cast(_Float16, (unsigned short)(w[i]   >> 16));
        hv1[i] = __builtin_bit_cast(_Float16, (unsigned short)(w[8+i] >> 16));
      }
      *(half8*)&h_lds[cb*SH + cj0]     = hv0;
      *(half8*)&h_lds[cb*SH + cj0 + 8] = hv1;
    }
    LDS_BARRIER();   // staged h visible

    // ---- dots ----
    float acc0 = 0.f, acc1 = 0.f;
    #pragma unroll 4
    for (int k8 = 0; k8 < H_/8; ++k8) {
      half8 hv = Hr[k8];
      half8 u0 = Ur0[k8];
      half8 u1 = Ur1[k8];
      #pragma unroll
      for (int i = 0; i < 4; ++i) {
        acc0 = fdot2_acc(h2(hv,i), h2(u0,i), acc0);
        acc1 = fdot2_acc(h2(hv,i), h2(u1,i), acc1);
      }
    }
    float pre0 = acc0 + xg0;     // gh0: a-gate   gh1: i-gate
    float pre1 = acc1 + xg1;     // gh0: f-gate   gh1: o-gate

    float act0 = (gh == 0) ? fast_tanh(pre0) : fast_sigmoid(pre0);
    float act1 = fast_sigmoid(pre1);

    if (gh == 1) {
      act_buf[local*2    ] = act0;   // sigmoid(i)
      act_buf[local*2 + 1] = act1;   // sigmoid(o)
    }
    LDS_BARRIER();   // act_buf visible; h_lds reads done

    // ---- finish + dual publish (gh0 only) ----
    if (gh == 0) {
      float iv = act_buf[local*2];
      float ov = act_buf[local*2 + 1];
      float cn = fmaf(act1, c_reg, iv * act0);   // f*c + i*a
      c_reg = cn;
      float hval = ov * fast_tanh(cn);
      if (t + 1 < T_) {
        unsigned wv = ((unsigned)__builtin_bit_cast(unsigned short, (_Float16)hval) << 16)
                    | ((unsigned)(t + 1) & 0xFFFFu);
        unsigned idx = ((unsigned)((t + 1) & 1))*32768u + (unsigned)grp*4096u
                     + (unsigned)member*128u + (unsigned)local;
        *(volatile unsigned*)&fast_buf[idx] = wv;   // write-through -> local L2
        __hip_atomic_store(&true_buf[idx], wv,      // truth -> MALL
                           __ATOMIC_RELAXED, __HIP_MEMORY_SCOPE_AGENT);
      }
      out[((size_t)bglob * T_ + t) * H_ + j] = hval;   // in poll shadow
    }

    // ---- prefetch XG for t+1 (lands during next poll) ----
    if (t + 1 < T_) {
      size_t xbn = ((size_t)(t + 1) * B_ + bglob) * NG;
      xg0 = (float)XG[xbn + (size_t)gh*H_ + j];
      xg1 = (float)XG[xbn + (size_t)(gh + 2)*H_ + j];
    }
  }
}

// ---------------------------------------------------------------------------
extern "C" void kernel_launch(void* const* d_in, const int* in_sizes, int n_in,
                              void* d_out, int out_size, void* d_ws, size_t ws_size,
                              hipStream_t stream)
{
  const float* x  = (const float*)d_in[0];
  const float* Wc = (const float*)d_in[1];
  const float* Wi = (const float*)d_in[2];
  const float* Wf = (const float*)d_in[3];
  const float* Wo = (const float*)d_in[4];
  const float* Uc = (const float*)d_in[5];
  const float* Ui = (const float*)d_in[6];
  const float* Uf = (const float*)d_in[7];
  const float* Uo = (const float*)d_in[8];
  const float* bc = (const float*)d_in[9];
  const float* bi = (const float*)d_in[10];
  const float* bf2= (const float*)d_in[11];
  const float* bo = (const float*)d_in[12];
  float* out = (float*)d_out;

  const size_t XG_BYTES  = (size_t)T_ * B_ * NG * sizeof(_Float16);  // 128 MiB
  const size_t BUF_BYTES = (size_t)2 * 8 * 4096 * sizeof(unsigned);  // 256 KiB each

  if (ws_size < XG_BYTES + 2*BUF_BYTES) return;

  _Float16* XG       = (_Float16*)d_ws;
  unsigned* fast_buf = (unsigned*)((char*)d_ws + XG_BYTES);
  unsigned* true_buf = (unsigned*)((char*)d_ws + XG_BYTES + BUF_BYTES);

  // tag 0 == "h^0 = 0 ready"; re-zeroed every launch
  (void)hipMemsetAsync(fast_buf, 0, 2*BUF_BYTES, stream);

  proj_kernel<<<dim3((T_*B_/64) * (NG/64)), dim3(256), 0, stream>>>(
      x, Wc, Wi, Wf, Wo, bc, bi, bf2, bo, XG);

  const int lds_bytes = 72*SH*2 + 256*4;   // 75,904 B
  (void)hipFuncSetAttribute(reinterpret_cast<const void*>(scan_kernel),
                      hipFuncAttributeMaxDynamicSharedMemorySize, lds_bytes);
  scan_kernel<<<dim3(256), dim3(256), lds_bytes, stream>>>(
      XG, Uc, Ui, Uf, Uo, out, fast_buf, true_buf);
}

// Round 11
// 2754.266 us; speedup vs baseline: 1.2889x; 1.2889x over previous
//
#include <hip/hip_runtime.h>
#include <cstdint>
#include <cstddef>

typedef _Float16 half8  __attribute__((ext_vector_type(8)));
typedef _Float16 half2v __attribute__((ext_vector_type(2)));
typedef float    floatx4 __attribute__((ext_vector_type(4)));

#define B_  64
#define T_  512
#define D_  512
#define H_  512
#define NG  2048   // 4*H

#if defined(__has_builtin)
#if __has_builtin(__builtin_amdgcn_fdot2)
#define HAVE_FDOT2 1
#endif
#endif

static __device__ __forceinline__ float fdot2_acc(half2v a, half2v b, float c) {
#ifdef HAVE_FDOT2
  return __builtin_amdgcn_fdot2(a, b, c, false);
#else
  return fmaf((float)a[0], (float)b[0], fmaf((float)a[1], (float)b[1], c));
#endif
}
static __device__ __forceinline__ half2v h2(half8 v, int i) {
  half2v r; r[0] = v[2*i]; r[1] = v[2*i+1]; return r;
}
static __device__ __forceinline__ float fast_sigmoid(float x) {
  return 1.0f / (1.0f + __expf(-x));
}
static __device__ __forceinline__ float fast_tanh(float x) {
  x = fminf(15.0f, fmaxf(-15.0f, x));
  float e = __expf(2.0f * x);
  return (e - 1.0f) / (e + 1.0f);
}

// LDS-only barrier: drains lgkmcnt but NOT vmcnt (global ops stay in flight).
#define LDS_BARRIER() do {                                   \
    asm volatile("s_waitcnt lgkmcnt(0)" ::: "memory");       \
    __builtin_amdgcn_s_barrier();                            \
  } while (0)

// ---------------------------------------------------------------------------
// Kernel 1: input projections (unchanged — measured ~0.17 ms)
// ---------------------------------------------------------------------------
__global__ __launch_bounds__(256) void proj_kernel(
    const float* __restrict__ x,
    const float* __restrict__ Wc, const float* __restrict__ Wi,
    const float* __restrict__ Wf, const float* __restrict__ Wo,
    const float* __restrict__ bc, const float* __restrict__ bi,
    const float* __restrict__ bf2, const float* __restrict__ bo,
    _Float16* __restrict__ XG)
{
  const int tiles_n = NG / 64;
  int tM = blockIdx.x / tiles_n;
  int tN = blockIdx.x % tiles_n;
  int r0 = tM * 64;
  int t0 = r0 >> 6;
  int n0 = tN * 64;
  int g  = n0 >> 9;
  const float* W    = (g==0) ? Wc : (g==1) ? Wi : (g==2) ? Wf : Wo;
  const float* bias = (g==0) ? bc : (g==1) ? bi : (g==2) ? bf2 : bo;
  int j0 = n0 & (H_-1);

  __shared__ _Float16 Al[64*40];
  __shared__ _Float16 Bl[64*40];

  int tid  = threadIdx.x;
  int wave = tid >> 6;
  int lane = tid & 63;

  floatx4 acc[4] = {};

  int arow = tid >> 2;
  int ak0  = (tid & 3) * 8;
  const float* xsrc = x + ((size_t)arow * T_ + t0) * D_;

  int bcol = tid & 63;
  int bk0  = (tid >> 6) * 8;

  for (int k0 = 0; k0 < D_; k0 += 32) {
    half8 av;
    #pragma unroll
    for (int i = 0; i < 8; ++i) av[i] = (_Float16)xsrc[k0 + ak0 + i];
    *(half8*)&Al[arow*40 + ak0] = av;

    half8 bv;
    #pragma unroll
    for (int i = 0; i < 8; ++i)
      bv[i] = (_Float16)W[(size_t)(k0 + bk0 + i) * H_ + j0 + bcol];
    *(half8*)&Bl[bcol*40 + bk0] = bv;

    __syncthreads();

    half8 afrag = *(half8*)&Al[(wave*16 + (lane & 15))*40 + (lane >> 4)*8];
    #pragma unroll
    for (int ct = 0; ct < 4; ++ct) {
      half8 bfrag = *(half8*)&Bl[(ct*16 + (lane & 15))*40 + (lane >> 4)*8];
      acc[ct] = __builtin_amdgcn_mfma_f32_16x16x32_f16(afrag, bfrag, acc[ct], 0, 0, 0);
    }
    __syncthreads();
  }

  #pragma unroll
  for (int ct = 0; ct < 4; ++ct) {
    int col = n0 + ct*16 + (lane & 15);
    float bvs = bias[col & (H_-1)];
    #pragma unroll
    for (int i = 0; i < 4; ++i) {
      int row = r0 + wave*16 + (lane >> 4)*4 + i;
      XG[(size_t)row * NG + col] = (_Float16)(acc[ct][i] + bvs);
    }
  }
}

// ---------------------------------------------------------------------------
// Kernel 2: persistent scan, v11 — 2-way batch-set pipeline over R9 fabric.
//   Group (blockIdx&7) owns 8 batches, split into sets A=b0..3, B=b4..7.
//   Per iteration: phase(A,t) then phase(B,t); each set's publish->poll gap
//   is the opposite set's phase -> MALL latency hidden under compute.
//   Thread map per phase: lane = g*16+jj, wave = batch. h reads = LDS
//   broadcast; U chunk-major [k8][64] = stride-1 conflict-free; gate
//   combine via 3 intra-wave shfl_xor (no barrier, no act_buf).
//   Sync fabric: R9's tagged words, compiler-emitted agent atomics only.
// ---------------------------------------------------------------------------
__global__ __launch_bounds__(256) void scan_kernel(
    const _Float16* __restrict__ XG,
    const float* __restrict__ Uc, const float* __restrict__ Ui,
    const float* __restrict__ Uf, const float* __restrict__ Uo,
    float* __restrict__ out, unsigned* __restrict__ dbuf)
{
  extern __shared__ _Float16 lds[];
  _Float16* U2    = lds;            // [k8][row=g*16+jj][8] : 64*64*8 halfs = 64KB
  _Float16* h_lds = lds + 32768;    // [set][b][512] : 2*4*512 halfs = 8KB

  int tid = threadIdx.x;
  int grp = blockIdx.x & 7;
  int member = blockIdx.x >> 3;
  int j0 = member * 16;

  { // one-time: stage U chunk-major, f32 -> f16
    int jj = tid & 15;
    int kk = tid >> 4;   // 16 k-slots
    #pragma unroll
    for (int g = 0; g < 4; ++g) {
      const float* U = (g==0) ? Uc : (g==1) ? Ui : (g==2) ? Uf : Uo;
      for (int k = kk; k < H_; k += 16)
        U2[((size_t)(k >> 3)*64 + g*16 + jj)*8 + (k & 7)] =
            (_Float16)U[(size_t)k * H_ + j0 + jj];
    }
  }
  __syncthreads();

  int lane = tid & 63;
  int wb   = tid >> 6;            // wave index = batch within set (0..3)
  int g    = lane >> 4;           // gate 0..3 (a,i,f,o)
  int jj   = lane & 15;
  int j    = j0 + jj;
  bool isg0 = (g == 0);

  // consumer staging geometry: thread covers 8 words = (cb, col0..col0+7)
  int cb   = tid >> 6;
  int col0 = (tid & 63) * 8;

  int bgA = grp*8 + wb;           // set A batch
  int bgB = grp*8 + 4 + wb;       // set B batch

  float cA = 0.0f, cB = 0.0f;
  float xgA, xgB;
  {
    xgA = (float)XG[((size_t)bgA) * NG + (size_t)g*H_ + j];
    xgB = (float)XG[((size_t)bgB) * NG + (size_t)g*H_ + j];
  }

  const half8* hrowA = (const half8*)&h_lds[0    + wb*512];
  const half8* hrowB = (const half8*)&h_lds[2048 + wb*512];
  const half8* urow  = (const half8*)U2;

  for (int t = 0; t < T_; ++t) {
    unsigned want = (unsigned)t & 0xFFFFu;
    unsigned long long want2 = (unsigned long long)want * 0x0000000100000001ull;

    #pragma unroll
    for (int s = 0; s < 2; ++s) {
      // ---- poll + stage set s at step t ----
      {
        unsigned base = ((unsigned)(s*2 + (t & 1))*8u + (unsigned)grp)*2048u
                      + (unsigned)tid*8u;
        const unsigned long long* src4 = (const unsigned long long*)(dbuf + base);
        unsigned long long w4[4];
        unsigned pend = 0xFu;
        for (;;) {
          #pragma unroll
          for (int q = 0; q < 4; ++q)
            if (pend & (1u << q))
              w4[q] = __hip_atomic_load(src4 + q, __ATOMIC_RELAXED,
                                        __HIP_MEMORY_SCOPE_AGENT);
          unsigned npend = 0;
          #pragma unroll
          for (int q = 0; q < 4; ++q)
            if ((pend & (1u << q)) &&
                ((w4[q] ^ want2) & 0x0000FFFF0000FFFFull))
              npend |= 1u << q;
          if (!npend) break;
          pend = npend;
          __builtin_amdgcn_s_sleep(1);
        }
        half8 hv;
        #pragma unroll
        for (int q = 0; q < 4; ++q) {
          hv[2*q]   = __builtin_bit_cast(_Float16, (unsigned short)(w4[q] >> 16));
          hv[2*q+1] = __builtin_bit_cast(_Float16, (unsigned short)(w4[q] >> 48));
        }
        *(half8*)&h_lds[s*2048 + cb*512 + col0] = hv;
      }
      LDS_BARRIER();   // staged h visible; also protects other set's h region

      int bglob = (s == 0) ? bgA : bgB;
      float xg  = (s == 0) ? xgA : xgB;

      // ---- prefetch XG for t+1 (in flight during dots) ----
      float xgn = 0.f;
      if (t + 1 < T_)
        xgn = (float)XG[((size_t)(t + 1)*B_ + bglob) * NG + (size_t)g*H_ + j];

      // ---- dot: h_row(batch wb) . U2_row(lane) ----
      const half8* hrow = (s == 0) ? hrowA : hrowB;
      float acc = 0.f;
      #pragma unroll 8
      for (int k8 = 0; k8 < 64; ++k8) {
        half8 hv8 = hrow[k8];              // broadcast (all lanes same addr)
        half8 uv8 = urow[k8*64 + lane];    // stride-1 across wave: no conflict
        #pragma unroll
        for (int i = 0; i < 4; ++i)
          acc = fdot2_acc(h2(hv8, i), h2(uv8, i), acc);
      }
      float pre = acc + xg;

      // ---- per-gate activation + intra-wave combine (no barrier) ----
      float act = isg0 ? fast_tanh(pre) : fast_sigmoid(pre);
      float t16 = __shfl_xor(act, 16);   // g0<-i, g2<-o
      float ia  = act * t16;             // at g0: tanh(a)*sig(i)
      float fv  = __shfl_xor(act, 32);   // at g0: sig(f)
      float ov  = __shfl_xor(t16, 32);   // at g0: sig(o)

      if (isg0) {
        float c_old = (s == 0) ? cA : cB;
        float cn = fmaf(fv, c_old, ia);
        if (s == 0) cA = cn; else cB = cn;
        float hval = ov * fast_tanh(cn);
        if (t + 1 < T_) {   // publish FIRST (critical path)
          unsigned wv = ((unsigned)__builtin_bit_cast(unsigned short,
                              (_Float16)hval) << 16)
                      | ((unsigned)(t + 1) & 0xFFFFu);
          unsigned pidx = ((unsigned)(s*2 + ((t + 1) & 1))*8u + (unsigned)grp)*2048u
                        + (unsigned)(wb*512) + (unsigned)j;
          __hip_atomic_store(&dbuf[pidx], wv,
                             __ATOMIC_RELAXED, __HIP_MEMORY_SCOPE_AGENT);
        }
        out[((size_t)bglob * T_ + t) * H_ + j] = hval;   // in shadow
      }

      if (s == 0) xgA = xgn; else xgB = xgn;
    }
  }
}

// ---------------------------------------------------------------------------
extern "C" void kernel_launch(void* const* d_in, const int* in_sizes, int n_in,
                              void* d_out, int out_size, void* d_ws, size_t ws_size,
                              hipStream_t stream)
{
  const float* x  = (const float*)d_in[0];
  const float* Wc = (const float*)d_in[1];
  const float* Wi = (const float*)d_in[2];
  const float* Wf = (const float*)d_in[3];
  const float* Wo = (const float*)d_in[4];
  const float* Uc = (const float*)d_in[5];
  const float* Ui = (const float*)d_in[6];
  const float* Uf = (const float*)d_in[7];
  const float* Uo = (const float*)d_in[8];
  const float* bc = (const float*)d_in[9];
  const float* bi = (const float*)d_in[10];
  const float* bf2= (const float*)d_in[11];
  const float* bo = (const float*)d_in[12];
  float* out = (float*)d_out;

  const size_t XG_BYTES = (size_t)T_ * B_ * NG * sizeof(_Float16);      // 128 MiB
  const size_t DB_BYTES = (size_t)2 * 2 * 8 * 2048 * sizeof(unsigned);  // 256 KiB

  if (ws_size < XG_BYTES + DB_BYTES) return;

  _Float16* XG   = (_Float16*)d_ws;
  unsigned* dbuf = (unsigned*)((char*)d_ws + XG_BYTES);

  // tag 0 == "h^0 = 0 ready"; re-zeroed every launch (kills replay aliasing)
  (void)hipMemsetAsync(dbuf, 0, DB_BYTES, stream);

  proj_kernel<<<dim3((T_*B_/64) * (NG/64)), dim3(256), 0, stream>>>(
      x, Wc, Wi, Wf, Wo, bc, bi, bf2, bo, XG);

  const int lds_bytes = (32768 + 2*2048) * (int)sizeof(_Float16);  // 73,728 B
  (void)hipFuncSetAttribute(reinterpret_cast<const void*>(scan_kernel),
                      hipFuncAttributeMaxDynamicSharedMemorySize, lds_bytes);
  scan_kernel<<<dim3(256), dim3(256), lds_bytes, stream>>>(
      XG, Uc, Ui, Uf, Uo, out, dbuf);
}